// Round 8
// 1016.233 us; speedup vs baseline: 1.3839x; 1.0157x over previous
//
#include <hip/hip_runtime.h>

// ---------------------------------------------------------------------------
// B=8, N=1024, CIN=2048, HID=1024, HC=64, LV=512, NH_SSD=16, HD=128, DS=64.
// Encoder rows = 4096. Decoder collapsed to 1 row/batch. All large GEMMs:
// split-bf16 MFMA (NPASS=3 f32-grade; NPASS=2 A-exact; NPASS=1 bf16),
// staged via __builtin_amdgcn_global_load_lds width=16 (DIRECT path).
// DIRECT GEMM: double-buffered 64KB LDS (2 blocks/CU), vmcnt(0)+barrier,
// source-swizzled staging, XCD-chunked bijective block remap. Split-K x2
// for 256-block GEMMs. Round 8: NPASS=2 for HCQ decoder GEMM (A=+-1 exact,
// bit-identical, -1/3 MFMA); 4 more launch fusions (prep+pairifyA,
// skred_rms+pairify(exp_W), cuma into gemm_f32, dxm_ln into DXV-LN).
// ---------------------------------------------------------------------------

typedef short bf16x8 __attribute__((ext_vector_type(8)));
typedef float f32x4 __attribute__((ext_vector_type(4)));

__device__ __forceinline__ unsigned short bf16_rne(float f) {
    unsigned u = __float_as_uint(f);
    unsigned r = u + 0x7FFFu + ((u >> 16) & 1u);
    return (unsigned short)(r >> 16);
}
__device__ __forceinline__ float bf16_tof(unsigned short h) {
    return __uint_as_float(((unsigned)h) << 16);
}
__device__ __forceinline__ void store_pair(unsigned short* dst, long long row,
                                           int width, int c, float v) {
    unsigned short hi = bf16_rne(v);
    unsigned short lo = bf16_rne(v - bf16_tof(hi));
    long long base = row * (2LL * width);
    dst[base + c] = hi;
    dst[base + width + c] = lo;
}
// Async global->LDS, 16B per lane. LDS dest = wave-uniform base + lane*16.
__device__ __forceinline__ void async_ld16(const unsigned short* g, unsigned short* l) {
    __builtin_amdgcn_global_load_lds(
        (const __attribute__((address_space(1))) unsigned int*)g,
        (__attribute__((address_space(3))) unsigned int*)l, 16, 0, 0);
}

// XCD-chunked bijective block remap (T1). Identity when nwg % 8 != 0.
__device__ __forceinline__ void xcd_remap(int& bx, int& by) {
    const int Gx = gridDim.x;
    const int nwg = Gx * gridDim.y;
    if ((nwg & 7) != 0) return;
    int lin = bx + Gx * by;
    int logical = (lin & 7) * (nwg >> 3) + (lin >> 3);
    bx = logical % Gx;
    by = logical / Gx;
}

// ---------------------------------------------------------------------------
// Reduction helpers (blockDim 256)
// ---------------------------------------------------------------------------
__device__ __forceinline__ float block_sum256(float v) {
    #pragma unroll
    for (int o = 32; o > 0; o >>= 1) v += __shfl_xor(v, o, 64);
    __shared__ float sm[4];
    int w = threadIdx.x >> 6;
    __syncthreads();
    if ((threadIdx.x & 63) == 0) sm[w] = v;
    __syncthreads();
    return sm[0] + sm[1] + sm[2] + sm[3];
}
__device__ __forceinline__ float block_max256(float v) {
    #pragma unroll
    for (int o = 32; o > 0; o >>= 1) v = fmaxf(v, __shfl_xor(v, o, 64));
    __shared__ float smx[4];
    int w = threadIdx.x >> 6;
    __syncthreads();
    if ((threadIdx.x & 63) == 0) smx[w] = v;
    __syncthreads();
    return fmaxf(fmaxf(smx[0], smx[1]), fmaxf(smx[2], smx[3]));
}

// ---------------------------------------------------------------------------
// Split-bf16 MFMA GEMM. C[m,n] = alpha * sum_k A[m,k]*B[n,k] (+bias)(+res)
// NPASS=3: hh+lh+hl (f32-grade). NPASS=2: hh+hl (A exactly representable in
// bf16, e.g. +-1 quantized; bit-identical to NPASS=3 with A-lo==0).
// NPASS=1: hh only.
// OUT=0: f32 C. OUT=1: split-pair C. OUT=2: transposed split-pair per
// 512-row batch.
// ---------------------------------------------------------------------------
template<int NPASS, int OUT, bool DIRECT>
__global__ __launch_bounds__(256, 2) void gemm_bf16_k(
    int M, int N, int K,
    const unsigned short* __restrict__ A2, int lda2, int aLo, long long sAb, long long sAh,
    const unsigned short* __restrict__ B2, int ldb2, int bLo, long long sBb, long long sBh,
    void* __restrict__ Cv, int ldc, int cLo, long long sCb, long long sCh,
    const float* __restrict__ bias, const float* __restrict__ res, int ldr,
    float alpha, int nh)
{
    constexpr int ST   = DIRECT ? 32 : 40;
    constexpr int NARR = (NPASS == 3) ? 4 : ((NPASS == 2) ? 3 : 2);
    constexpr int NB   = DIRECT ? 2 : 1;
    constexpr int O_AH = 0;
    constexpr int O_BH = 128 * ST;
    constexpr int O_AL = 2 * 128 * ST;
    constexpr int O_BL = ((NPASS == 3) ? 3 : 2) * 128 * ST;
    constexpr int BUFSZ = 128 * ST * NARR;
    __shared__ unsigned short SM[NB * BUFSZ];

    const int z  = blockIdx.z;
    const int bb = z / nh, hh = z - bb * nh;
    A2 += bb * sAb + hh * sAh;
    B2 += bb * sBb + hh * sBh;

    int bx = blockIdx.x, by = blockIdx.y;
    xcd_remap(bx, by);
    const int t    = threadIdx.x;
    const int m0   = by * 128;
    const int n0   = bx * 128;
    const int lane = t & 63, wave = t >> 6;
    const int wm   = (wave >> 1) * 64, wn = (wave & 1) * 64;
    const int lr   = lane & 15, quad = lane >> 4;

    f32x4 acc[4][4];
    #pragma unroll
    for (int i = 0; i < 4; ++i)
        #pragma unroll
        for (int j = 0; j < 4; ++j) acc[i][j] = (f32x4){0.f, 0.f, 0.f, 0.f};

    if constexpr (DIRECT) {
        const int drow  = lane >> 2;                       // row in 16-chunk
        const int dcswz = (((lane & 3) ^ ((lane >> 2) & 3) ^ ((lane >> 4) & 3)) << 3);
        const int rsw   = ((quad ^ ((lr & 3) ^ (lr >> 2))) << 3);

        auto stage = [&](int k0, int buf) {
            unsigned short* bp = &SM[buf * BUFSZ];
            #pragma unroll
            for (int j = 0; j < 2; ++j) {
                int rr = wave * 32 + j * 16;               // chunk base row
                int gr = rr + drow;
                const unsigned short* gA = A2 + (long long)(m0 + gr) * lda2 + k0 + dcswz;
                async_ld16(gA, &bp[O_AH + rr * 32]);
                if (NPASS == 3) async_ld16(gA + aLo, &bp[O_AL + rr * 32]);
                const unsigned short* gB = B2 + (long long)(n0 + gr) * ldb2 + k0 + dcswz;
                async_ld16(gB, &bp[O_BH + rr * 32]);
                if (NPASS >= 2) async_ld16(gB + bLo, &bp[O_BL + rr * 32]);
            }
        };

        const int nt = K >> 5;
        stage(0, 0);
        int cur = 0;
        for (int it = 0; it < nt; ++it) {
            asm volatile("s_waitcnt vmcnt(0)" ::: "memory");
            __builtin_amdgcn_s_barrier();
            if (it + 1 < nt) stage((it + 1) << 5, cur ^ 1);

            const unsigned short* bp = &SM[cur * BUFSZ];
            bf16x8 ah[4], bh[4], al[4], bl[4];
            #pragma unroll
            for (int i = 0; i < 4; ++i) {
                int ra = O_AH + (wm + i * 16 + lr) * 32 + rsw;
                int rb = O_BH + (wn + i * 16 + lr) * 32 + rsw;
                ah[i] = *(const bf16x8*)&bp[ra];
                bh[i] = *(const bf16x8*)&bp[rb];
                if (NPASS == 3) al[i] = *(const bf16x8*)&bp[ra + (O_AL - O_AH)];
                if (NPASS >= 2) bl[i] = *(const bf16x8*)&bp[rb + (O_BL - O_BH)];
            }
            #pragma unroll
            for (int mi = 0; mi < 4; ++mi)
                #pragma unroll
                for (int ni = 0; ni < 4; ++ni) {
                    acc[mi][ni] = __builtin_amdgcn_mfma_f32_16x16x32_bf16(
                        ah[mi], bh[ni], acc[mi][ni], 0, 0, 0);
                    if (NPASS == 3)
                        acc[mi][ni] = __builtin_amdgcn_mfma_f32_16x16x32_bf16(
                            al[mi], bh[ni], acc[mi][ni], 0, 0, 0);
                    if (NPASS >= 2)
                        acc[mi][ni] = __builtin_amdgcn_mfma_f32_16x16x32_bf16(
                            ah[mi], bl[ni], acc[mi][ni], 0, 0, 0);
                }
            cur ^= 1;
        }
    } else {
        // ---- ragged reg-staging path ----
        const int srow = t >> 2;          // row 0..63 (+64)
        const int scol = (t & 3) * 8;

        for (int k0 = 0; k0 < K; k0 += 32) {
            __syncthreads();
            #pragma unroll
            for (int half = 0; half < 2; ++half) {
                int r = srow + half * 64;
                const unsigned short* pA = A2 + (long long)(m0 + r) * lda2 + k0 + scol;
                *(uint4*)&SM[O_AH + r * ST + scol] = *(const uint4*)pA;
                if (NPASS == 3)
                    *(uint4*)&SM[O_AL + r * ST + scol] = *(const uint4*)(pA + aLo);
                int rb = n0 + r;
                uint4 vh = {0u, 0u, 0u, 0u}, vl = {0u, 0u, 0u, 0u};
                if (rb < N) {
                    const unsigned short* pB = B2 + (long long)rb * ldb2 + k0 + scol;
                    vh = *(const uint4*)pB;
                    if (NPASS >= 2) vl = *(const uint4*)(pB + bLo);
                }
                *(uint4*)&SM[O_BH + r * ST + scol] = vh;
                if (NPASS >= 2) *(uint4*)&SM[O_BL + r * ST + scol] = vl;
            }
            __syncthreads();

            bf16x8 ah[4], bh[4], al[4], bl[4];
            #pragma unroll
            for (int i = 0; i < 4; ++i) {
                int ra = (wm + i * 16 + lr) * ST + quad * 8;
                int rb = (wn + i * 16 + lr) * ST + quad * 8;
                ah[i] = *(const bf16x8*)&SM[O_AH + ra];
                bh[i] = *(const bf16x8*)&SM[O_BH + rb];
                if (NPASS == 3) al[i] = *(const bf16x8*)&SM[O_AL + ra];
                if (NPASS >= 2) bl[i] = *(const bf16x8*)&SM[O_BL + rb];
            }
            #pragma unroll
            for (int mi = 0; mi < 4; ++mi)
                #pragma unroll
                for (int ni = 0; ni < 4; ++ni) {
                    acc[mi][ni] = __builtin_amdgcn_mfma_f32_16x16x32_bf16(
                        ah[mi], bh[ni], acc[mi][ni], 0, 0, 0);
                    if (NPASS == 3)
                        acc[mi][ni] = __builtin_amdgcn_mfma_f32_16x16x32_bf16(
                            al[mi], bh[ni], acc[mi][ni], 0, 0, 0);
                    if (NPASS >= 2)
                        acc[mi][ni] = __builtin_amdgcn_mfma_f32_16x16x32_bf16(
                            ah[mi], bl[ni], acc[mi][ni], 0, 0, 0);
                }
        }
    }

    // D layout: col = lane&15, row = quad*4 + r
    if (OUT == 0) {
        float* C = (float*)Cv + bb * sCb + hh * sCh;
        #pragma unroll
        for (int mi = 0; mi < 4; ++mi)
            #pragma unroll
            for (int ni = 0; ni < 4; ++ni) {
                int col = n0 + wn + ni * 16 + lr;
                if (col >= N) continue;
                float bv = bias ? bias[col] : 0.f;
                #pragma unroll
                for (int r = 0; r < 4; ++r) {
                    int row = m0 + wm + mi * 16 + quad * 4 + r;
                    float v = alpha * acc[mi][ni][r] + bv;
                    if (res) v += res[(long long)row * ldr + col];
                    C[(long long)row * ldc + col] = v;
                }
            }
    } else if (OUT == 1) {
        unsigned short* C = (unsigned short*)Cv + bb * sCb + hh * sCh;
        #pragma unroll
        for (int mi = 0; mi < 4; ++mi)
            #pragma unroll
            for (int ni = 0; ni < 4; ++ni) {
                int col = n0 + wn + ni * 16 + lr;
                if (col >= N) continue;
                float bv = bias ? bias[col] : 0.f;
                #pragma unroll
                for (int r = 0; r < 4; ++r) {
                    int row = m0 + wm + mi * 16 + quad * 4 + r;
                    float v = alpha * acc[mi][ni][r] + bv;
                    if (res) v += res[(long long)row * ldr + col];
                    unsigned short hi = bf16_rne(v);
                    unsigned short lo = bf16_rne(v - bf16_tof(hi));
                    long long p = (long long)row * ldc + col;
                    C[p] = hi;
                    C[p + cLo] = lo;
                }
            }
    } else {  // OUT == 2: transposed pairs per 512-row batch
        unsigned short* C = (unsigned short*)Cv;
        #pragma unroll
        for (int mi = 0; mi < 4; ++mi)
            #pragma unroll
            for (int ni = 0; ni < 4; ++ni) {
                int col = n0 + wn + ni * 16 + lr;
                if (col >= N) continue;
                int row0 = m0 + wm + mi * 16 + quad * 4;
                int b = row0 >> 9, seq0 = row0 & 511;
                ushort4 h4, l4;
                unsigned short* hp = (unsigned short*)&h4;
                unsigned short* lp = (unsigned short*)&l4;
                #pragma unroll
                for (int r = 0; r < 4; ++r) {
                    float v = acc[mi][ni][r];
                    unsigned short hi = bf16_rne(v);
                    hp[r] = hi;
                    lp[r] = bf16_rne(v - bf16_tof(hi));
                }
                long long p = b * sCb + (long long)col * ldc + seq0;
                *(ushort4*)&C[p] = h4;
                *(ushort4*)&C[p + cLo] = l4;
            }
    }
}

// ---------------------------------------------------------------------------
// DIRECT pipelined split-K GEMM -> f32 partial planes.
// TR=0: partial[row*N + col]. TR=1: transposed partials (float4 along seq).
// ---------------------------------------------------------------------------
template<int NPASS, int TR>
__global__ __launch_bounds__(256, 2) void gemm_bf16_skd_k(
    int N, int KC,
    const unsigned short* __restrict__ A2, int lda2, int aLo,
    const unsigned short* __restrict__ B2, int ldb2, int bLo,
    float* __restrict__ P, long long sCk)
{
    constexpr int NARR = (NPASS == 3) ? 4 : 2;
    constexpr int O_AH = 0;
    constexpr int O_BH = 128 * 32;
    constexpr int O_AL = 2 * 128 * 32;
    constexpr int O_BL = 3 * 128 * 32;
    constexpr int BUFSZ = 128 * 32 * NARR;
    __shared__ unsigned short SM[2 * BUFSZ];

    int bx = blockIdx.x, by = blockIdx.y;
    xcd_remap(bx, by);
    const int t    = threadIdx.x;
    const int m0   = by * 128;
    const int n0   = bx * 128;
    const int kbeg = blockIdx.z * KC;
    const int lane = t & 63, wave = t >> 6;
    const int wm   = (wave >> 1) * 64, wn = (wave & 1) * 64;
    const int lr   = lane & 15, quad = lane >> 4;

    f32x4 acc[4][4];
    #pragma unroll
    for (int i = 0; i < 4; ++i)
        #pragma unroll
        for (int j = 0; j < 4; ++j) acc[i][j] = (f32x4){0.f, 0.f, 0.f, 0.f};

    const int drow  = lane >> 2;
    const int dcswz = (((lane & 3) ^ ((lane >> 2) & 3) ^ ((lane >> 4) & 3)) << 3);
    const int rsw   = ((quad ^ ((lr & 3) ^ (lr >> 2))) << 3);

    auto stage = [&](int k0, int buf) {
        unsigned short* bp = &SM[buf * BUFSZ];
        #pragma unroll
        for (int j = 0; j < 2; ++j) {
            int rr = wave * 32 + j * 16;
            int gr = rr + drow;
            const unsigned short* gA = A2 + (long long)(m0 + gr) * lda2 + k0 + dcswz;
            async_ld16(gA, &bp[O_AH + rr * 32]);
            if (NPASS == 3) async_ld16(gA + aLo, &bp[O_AL + rr * 32]);
            const unsigned short* gB = B2 + (long long)(n0 + gr) * ldb2 + k0 + dcswz;
            async_ld16(gB, &bp[O_BH + rr * 32]);
            if (NPASS == 3) async_ld16(gB + bLo, &bp[O_BL + rr * 32]);
        }
    };

    const int nt = KC >> 5;
    stage(kbeg, 0);
    int cur = 0;
    for (int it = 0; it < nt; ++it) {
        asm volatile("s_waitcnt vmcnt(0)" ::: "memory");
        __builtin_amdgcn_s_barrier();
        if (it + 1 < nt) stage(kbeg + ((it + 1) << 5), cur ^ 1);

        const unsigned short* bp = &SM[cur * BUFSZ];
        bf16x8 ah[4], bh[4], al[4], bl[4];
        #pragma unroll
        for (int i = 0; i < 4; ++i) {
            int ra = O_AH + (wm + i * 16 + lr) * 32 + rsw;
            int rb = O_BH + (wn + i * 16 + lr) * 32 + rsw;
            ah[i] = *(const bf16x8*)&bp[ra];
            bh[i] = *(const bf16x8*)&bp[rb];
            if (NPASS == 3) {
                al[i] = *(const bf16x8*)&bp[ra + (O_AL - O_AH)];
                bl[i] = *(const bf16x8*)&bp[rb + (O_BL - O_BH)];
            }
        }
        #pragma unroll
        for (int mi = 0; mi < 4; ++mi)
            #pragma unroll
            for (int ni = 0; ni < 4; ++ni) {
                acc[mi][ni] = __builtin_amdgcn_mfma_f32_16x16x32_bf16(
                    ah[mi], bh[ni], acc[mi][ni], 0, 0, 0);
                if (NPASS == 3) {
                    acc[mi][ni] = __builtin_amdgcn_mfma_f32_16x16x32_bf16(
                        al[mi], bh[ni], acc[mi][ni], 0, 0, 0);
                    acc[mi][ni] = __builtin_amdgcn_mfma_f32_16x16x32_bf16(
                        ah[mi], bl[ni], acc[mi][ni], 0, 0, 0);
                }
            }
        cur ^= 1;
    }

    float* Pc = P + (long long)blockIdx.z * sCk;
    if (TR == 0) {
        #pragma unroll
        for (int mi = 0; mi < 4; ++mi)
            #pragma unroll
            for (int ni = 0; ni < 4; ++ni) {
                int col = n0 + wn + ni * 16 + lr;
                #pragma unroll
                for (int r = 0; r < 4; ++r) {
                    int row = m0 + wm + mi * 16 + quad * 4 + r;
                    Pc[(long long)row * N + col] = acc[mi][ni][r];
                }
            }
    } else {
        #pragma unroll
        for (int mi = 0; mi < 4; ++mi)
            #pragma unroll
            for (int ni = 0; ni < 4; ++ni) {
                int col = n0 + wn + ni * 16 + lr;
                int row0 = m0 + wm + mi * 16 + quad * 4;
                int b = row0 >> 9, seq0 = row0 & 511;
                *(float4*)&Pc[(long long)b * ((long long)N * 512)
                              + (long long)col * 512 + seq0] =
                    *(float4*)&acc[mi][ni];
            }
    }
}

// ---------------------------------------------------------------------------
// Split-K ragged GEMM for thin-N ops (xproj N=144, hW N=64).
// ---------------------------------------------------------------------------
template<int NPASS>
__global__ __launch_bounds__(256, 2) void gemm_bf16_sk_k(
    int N, int KC,
    const unsigned short* __restrict__ A2, int lda2, int aLo,
    const unsigned short* __restrict__ B2, int ldb2, int bLo,
    float* __restrict__ C, long long sCk)
{
    constexpr int ST = 40;
    __shared__ unsigned short Ah[128 * ST];
    __shared__ unsigned short Bh[128 * ST];
    __shared__ unsigned short Al[128 * ST];
    __shared__ unsigned short Bl[128 * ST];

    int bx = blockIdx.x, by = blockIdx.y;
    xcd_remap(bx, by);
    const int t    = threadIdx.x;
    const int m0   = by * 128;
    const int n0   = bx * 128;
    const int kbeg = blockIdx.z * KC;
    const int lane = t & 63, wave = t >> 6;
    const int wm   = (wave >> 1) * 64, wn = (wave & 1) * 64;
    const int lr   = lane & 15, quad = lane >> 4;

    f32x4 acc[4][4];
    #pragma unroll
    for (int i = 0; i < 4; ++i)
        #pragma unroll
        for (int j = 0; j < 4; ++j) acc[i][j] = (f32x4){0.f, 0.f, 0.f, 0.f};

    const int srow = t >> 2;
    const int scol = (t & 3) * 8;

    for (int k0 = kbeg; k0 < kbeg + KC; k0 += 32) {
        __syncthreads();
        #pragma unroll
        for (int half = 0; half < 2; ++half) {
            int r = srow + half * 64;
            const unsigned short* pA = A2 + (long long)(m0 + r) * lda2 + k0 + scol;
            *(uint4*)&Ah[r * ST + scol] = *(const uint4*)pA;
            if (NPASS == 3)
                *(uint4*)&Al[r * ST + scol] = *(const uint4*)(pA + aLo);
            int rb = n0 + r;
            uint4 vh = {0u, 0u, 0u, 0u}, vl = {0u, 0u, 0u, 0u};
            if (rb < N) {
                const unsigned short* pB = B2 + (long long)rb * ldb2 + k0 + scol;
                vh = *(const uint4*)pB;
                if (NPASS == 3) vl = *(const uint4*)(pB + bLo);
            }
            *(uint4*)&Bh[r * ST + scol] = vh;
            if (NPASS == 3) *(uint4*)&Bl[r * ST + scol] = vl;
        }
        __syncthreads();

        bf16x8 ah[4], bh[4], al[4], bl[4];
        #pragma unroll
        for (int i = 0; i < 4; ++i) {
            int ra = (wm + i * 16 + lr) * ST + quad * 8;
            int rb = (wn + i * 16 + lr) * ST + quad * 8;
            ah[i] = *(const bf16x8*)&Ah[ra];
            bh[i] = *(const bf16x8*)&Bh[rb];
            if (NPASS == 3) {
                al[i] = *(const bf16x8*)&Al[ra];
                bl[i] = *(const bf16x8*)&Bl[rb];
            }
        }
        #pragma unroll
        for (int mi = 0; mi < 4; ++mi)
            #pragma unroll
            for (int ni = 0; ni < 4; ++ni) {
                acc[mi][ni] = __builtin_amdgcn_mfma_f32_16x16x32_bf16(
                    ah[mi], bh[ni], acc[mi][ni], 0, 0, 0);
                if (NPASS == 3) {
                    acc[mi][ni] = __builtin_amdgcn_mfma_f32_16x16x32_bf16(
                        al[mi], bh[ni], acc[mi][ni], 0, 0, 0);
                    acc[mi][ni] = __builtin_amdgcn_mfma_f32_16x16x32_bf16(
                        ah[mi], bl[ni], acc[mi][ni], 0, 0, 0);
                }
            }
    }

    float* Cc = C + (long long)blockIdx.z * sCk;
    #pragma unroll
    for (int mi = 0; mi < 4; ++mi)
        #pragma unroll
        for (int ni = 0; ni < 4; ++ni) {
            int col = n0 + wn + ni * 16 + lr;
            if (col >= N) continue;
            #pragma unroll
            for (int r = 0; r < 4; ++r) {
                int row = m0 + wm + mi * 16 + quad * 4 + r;
                Cc[(long long)row * N + col] = acc[mi][ni][r];
            }
        }
}

// ---- fused split-K reduce epilogues ----

// in-GEMM partials -> T (f32) + RMSNorm pairs HR2; blocks >= 4096 pairify
// exp_W -> exp_W2 (independent work fused into one launch).
__global__ __launch_bounds__(256) void skred_rms_pair_k(
    const float* __restrict__ P, long long sCk,
    float* __restrict__ T, unsigned short* __restrict__ HR2,
    const float* __restrict__ w,
    const float* __restrict__ expW, unsigned short* __restrict__ expW2)
{
    const int t = threadIdx.x;
    if (blockIdx.x >= 4096) {
        long long idx = (long long)(blockIdx.x - 4096) * 256 + t;
        long long r = idx >> 10;
        int c = (int)(idx & 1023);
        store_pair(expW2, r, 1024, c, expW[idx]);
        return;
    }
    long long r = blockIdx.x;
    long long base = r * 1024 + t * 4;
    float4 a = *(const float4*)&P[base];
    float4 bq = *(const float4*)&P[sCk + base];
    float v[4] = {a.x + bq.x, a.y + bq.y, a.z + bq.z, a.w + bq.w};
    *(float4*)&T[base] = *(float4*)v;
    float s = v[0]*v[0] + v[1]*v[1] + v[2]*v[2] + v[3]*v[3];
    s = block_sum256(s);
    float rs = 1.f / sqrtf(s * (1.f / 1024.f) + 1e-5f);
    #pragma unroll
    for (int e = 0; e < 4; ++e) {
        int c = t * 4 + e;
        store_pair(HR2, r, 1024, c, v[e] * rs * w[c]);
    }
}

// outp-GEMM: partials + bias + residual -> Y1 (f32) + LayerNorm pairs LNY2.
__global__ __launch_bounds__(256) void skred_ln_k(
    const float* __restrict__ P, long long sCk,
    const float* __restrict__ bias, const float* __restrict__ res,
    float* __restrict__ Y1, unsigned short* __restrict__ LNY2,
    const float* __restrict__ w, const float* __restrict__ b)
{
    long long r = blockIdx.x;
    const int t = threadIdx.x;
    long long base = r * 1024 + t * 4;
    float4 a  = *(const float4*)&P[base];
    float4 bq = *(const float4*)&P[sCk + base];
    float4 rv = *(const float4*)&res[base];
    float4 bi = *(const float4*)&bias[t * 4];
    float v[4] = {a.x + bq.x + rv.x + bi.x, a.y + bq.y + rv.y + bi.y,
                  a.z + bq.z + rv.z + bi.z, a.w + bq.w + rv.w + bi.w};
    *(float4*)&Y1[base] = *(float4*)v;
    float s = v[0] + v[1] + v[2] + v[3];
    s = block_sum256(s);
    float m = s * (1.f / 1024.f);
    float vs = 0.f;
    #pragma unroll
    for (int e = 0; e < 4; ++e) { float d = v[e] - m; vs += d * d; }
    vs = block_sum256(vs);
    float rs = 1.f / sqrtf(vs * (1.f / 1024.f) + 1e-5f);
    #pragma unroll
    for (int e = 0; e < 4; ++e) {
        int c = t * 4 + e;
        store_pair(LNY2, r, 1024, c, (v[e] - m) * rs * w[c] + b[c]);
    }
}

// xproj: 8-chunk reduce -> dtBC, plus softplus(dt_bias) -> DT for cols<16.
__global__ __launch_bounds__(256) void skred_dt_k(
    const float* __restrict__ P, long long sCk,
    const float* __restrict__ dt_bias,
    float* __restrict__ dtBC, float* __restrict__ DT, long long n)
{
    long long idx = (long long)blockIdx.x * 256 + threadIdx.x;
    if (idx >= n) return;
    float s = 0.f;
    #pragma unroll
    for (int c = 0; c < 8; ++c) s += P[c * sCk + idx];
    dtBC[idx] = s;
    long long row = idx / 144;
    int col = (int)(idx - row * 144);
    if (col < 16) {
        float xv = s + dt_bias[col];
        DT[row * 16 + col] = (xv > 20.f) ? xv : log1pf(expf(xv));
    }
}

// hW: 8-chunk reduce + h_b + LayerNorm64 + sign-quant -> HCQ2 pairs (lo=0).
__global__ __launch_bounds__(64) void skred_hc_k(
    const float* __restrict__ P, long long sCk,
    const float* __restrict__ h_b,
    const float* __restrict__ w, const float* __restrict__ b,
    unsigned short* __restrict__ HCQ2)
{
    int r = blockIdx.x, ln = threadIdx.x;
    long long base = (long long)r * 64 + ln;
    float v = 0.f;
    #pragma unroll
    for (int c = 0; c < 8; ++c) v += P[c * sCk + base];
    v += h_b[ln];
    float s = v;
    #pragma unroll
    for (int o = 32; o > 0; o >>= 1) s += __shfl_xor(s, o, 64);
    float m = s * (1.f / 64.f);
    float d = v - m;
    float vs = d * d;
    #pragma unroll
    for (int o = 32; o > 0; o >>= 1) vs += __shfl_xor(vs, o, 64);
    vs *= (1.f / 64.f);
    float hc = d * (1.f / sqrtf(vs + 1e-5f)) * w[ln] + b[ln];
    HCQ2[r * 128 + ln] = (hc > 0.f) ? 0x3F80 : 0xBF80;
    HCQ2[r * 128 + 64 + ln] = 0;
}

// pairs out, N=1024 layout (aWo epilogue): bias + residual -> Y22 pairs.
__global__ __launch_bounds__(256) void skredP_k(
    const float* __restrict__ P, long long sCk, int nchunk,
    const float* __restrict__ bias, const float* __restrict__ res,
    unsigned short* __restrict__ out2, long long n)
{
    long long idx = (long long)blockIdx.x * 256 + threadIdx.x;
    if (idx >= n) return;
    float s = 0.f;
    for (int c = 0; c < nchunk; ++c) s += P[c * sCk + idx];
    int col = (int)(idx & 1023);
    long long row = idx >> 10;
    if (bias) s += bias[col];
    if (res) s += res[idx];
    unsigned short hi = bf16_rne(s);
    unsigned short lo = bf16_rne(s - bf16_tof(hi));
    long long pos = row * 2048 + col;
    out2[pos] = hi;
    out2[pos + 1024] = lo;
}

// transposed pairs out (VT2 layout), partials TR=1.
__global__ __launch_bounds__(256) void skredT_k(
    const float* __restrict__ P, long long sCk, int nchunk,
    unsigned short* __restrict__ out2, long long n)
{
    long long idx = (long long)blockIdx.x * 256 + threadIdx.x;
    if (idx >= n) return;
    float s = 0.f;
    for (int c = 0; c < nchunk; ++c) s += P[c * sCk + idx];
    int seq = (int)(idx & 511);
    int col = (int)((idx >> 9) & 1023);
    int b   = (int)(idx >> 19);
    unsigned short hi = bf16_rne(s);
    unsigned short lo = bf16_rne(s - bf16_tof(hi));
    long long pos = (long long)b * 1048576 + (long long)col * 1024 + seq;
    out2[pos] = hi;
    out2[pos + 512] = lo;
}

// ---------------------------------------------------------------------------
// Fused SSD intra-chunk MFMA kernel, v4 (unchanged).
// ---------------------------------------------------------------------------
__global__ __launch_bounds__(256, 2) void ssd_mfma_k(
    const float* __restrict__ G, const float* __restrict__ CUMA,
    const float* __restrict__ DT, const unsigned short* __restrict__ XCT2,
    const float* __restrict__ Z, const float* __restrict__ Dv,
    unsigned short* __restrict__ YS2)
{
    __shared__ unsigned short Xh[3][128 * 32];
    __shared__ unsigned short Xl[3][128 * 32];
    __shared__ unsigned short Wh[2][64 * 32];
    __shared__ unsigned short Wl[2][64 * 32];
    __shared__ float Cs[512];
    __shared__ float Ds[512];
    const int q = blockIdx.x;
    const int h = blockIdx.y, b = blockIdx.z;
    const int t = threadIdx.x;
    const int lane = t & 63, wave = t >> 6;
    const int lr = lane & 15, quad = lane >> 4;

    const float* cbase = CUMA + (b * 16 + h) * 512;
    const float* dtb = DT + (long long)b * 512 * 16 + h;
    for (int s = t; s < 512; s += 256) {
        Cs[s] = cbase[s];
        Ds[s] = dtb[(long long)s * 16];
    }
    const float Dh = Dv[h];

    const int wr = t >> 2;
    const int sw = t & 3;
    const int wbase = wr * 32 + ((sw ^ ((wr >> 1) & 3)) << 3);
    const int frow = wave * 16 + lr;
    const int fbase = frow * 32 + ((quad ^ ((frow >> 1) & 3)) << 3);
    const int drow  = lane >> 2;
    const int dcswz = (((lane & 3) ^ ((lane >> 2) & 3) ^ ((lane >> 4) & 3)) << 3);
    const int xsw   = ((quad ^ ((lr & 3) ^ ((lr >> 2) & 3))) << 3);
    const unsigned short* XB = XCT2 + (long long)b * 2097152
                             + (long long)(h * 128) * 1024;
    __syncthreads();

    for (int ph = 0; ph < 2; ++ph) {
        const int mt = ph ? q : 7 - q;
        const int m0 = mt * 64;
        const int nt = (m0 >> 5) + 2;
        const int lglob = m0 + wr;
        const float cAl = Cs[lglob];
        const float* grow = G + ((long long)(b * 512 + lglob)) * 512;

        float pg[8], pc[8], pd[8];
        auto gen_load = [&](int k0g) {
            const int sb = k0g + sw * 8;
            float4 g0 = *(const float4*)(grow + sb);
            float4 g1 = *(const float4*)(grow + sb + 4);
            float4 c0 = *(const float4*)&Cs[sb];
            float4 c1 = *(const float4*)&Cs[sb + 4];
            float4 d0 = *(const float4*)&Ds[sb];
            float4 d1 = *(const float4*)&Ds[sb + 4];
            pg[0] = g0.x; pg[1] = g0.y; pg[2] = g0.z; pg[3] = g0.w;
            pg[4] = g1.x; pg[5] = g1.y; pg[6] = g1.z; pg[7] = g1.w;
            pc[0] = c0.x; pc[1] = c0.y; pc[2] = c0.z; pc[3] = c0.w;
            pc[4] = c1.x; pc[5] = c1.y; pc[6] = c1.z; pc[7] = c1.w;
            pd[0] = d0.x; pd[1] = d0.y; pd[2] = d0.z; pd[3] = d0.w;
            pd[4] = d1.x; pd[5] = d1.y; pd[6] = d1.z; pd[7] = d1.w;
        };
        auto gen_finish = [&](int k0g, int buf) {
            const int sb = k0g + sw * 8;
            const bool edge = (k0g + 32 > m0);
            unsigned short hv[8], lv[8];
            #pragma unroll
            for (int e = 0; e < 8; ++e) {
                float w = pg[e] * __expf(cAl - pc[e]) * pd[e];
                if (edge) {
                    int sg = sb + e;
                    w = (sg <= lglob) ? w : 0.f;
                    if (sg == lglob) w += Dh;
                }
                unsigned short hi = bf16_rne(w);
                hv[e] = hi;
                lv[e] = bf16_rne(w - bf16_tof(hi));
            }
            *(uint4*)&Wh[buf][wbase] = *(uint4*)hv;
            *(uint4*)&Wl[buf][wbase] = *(uint4*)lv;
        };
        auto stageX = [&](int k0, int buf) {
            #pragma unroll
            for (int j = 0; j < 2; ++j) {
                int rr = wave * 32 + j * 16;
                const unsigned short* gX =
                    XB + (long long)(rr + drow) * 1024 + k0 + dcswz;
                async_ld16(gX,       &Xh[buf][rr * 32]);
                async_ld16(gX + 512, &Xl[buf][rr * 32]);
            }
        };

        f32x4 acc[8];
        #pragma unroll
        for (int j = 0; j < 8; ++j) acc[j] = (f32x4){0.f, 0.f, 0.f, 0.f};

        gen_load(0);
        stageX(0, 0);
        if (nt > 1) stageX(32, 1);
        gen_finish(0, 0);
        if (nt > 1) asm volatile("s_waitcnt vmcnt(4)" ::: "memory");
        else        asm volatile("s_waitcnt vmcnt(0)" ::: "memory");
        asm volatile("s_waitcnt lgkmcnt(0)" ::: "memory");
        __builtin_amdgcn_s_barrier();

        for (int it = 0; it < nt; ++it) {
            const int xb = it % 3;
            const int wb = it & 1;
            if (it + 1 < nt) gen_load((it + 1) << 5);
            if (it + 2 < nt) stageX((it + 2) << 5, (it + 2) % 3);

            bf16x8 ah = *(const bf16x8*)&Wh[wb][fbase];
            bf16x8 al = *(const bf16x8*)&Wl[wb][fbase];
            const unsigned short* xhp = &Xh[xb][0];
            const unsigned short* xlp = &Xl[xb][0];
            #pragma unroll
            for (int ni = 0; ni < 8; ++ni) {
                int base = (ni * 16 + lr) * 32 + xsw;
                bf16x8 bh = *(const bf16x8*)&xhp[base];
                bf16x8 bl = *(const bf16x8*)&xlp[base];
                acc[ni] = __builtin_amdgcn_mfma_f32_16x16x32_bf16(
                    ah, bh, acc[ni], 0, 0, 0);
                acc[ni] = __builtin_amdgcn_mfma_f32_16x16x32_bf16(
                    al, bh, acc[ni], 0, 0, 0);
                acc[ni] = __builtin_amdgcn_mfma_f32_16x16x32_bf16(
                    ah, bl, acc[ni], 0, 0, 0);
            }
            if (it + 1 < nt) gen_finish((it + 1) << 5, wb ^ 1);
            if (it + 2 < nt) asm volatile("s_waitcnt vmcnt(4)" ::: "memory");
            else             asm volatile("s_waitcnt vmcnt(0)" ::: "memory");
            asm volatile("s_waitcnt lgkmcnt(0)" ::: "memory");
            __builtin_amdgcn_s_barrier();
        }

        const int row0 = m0 + wave * 16 + quad * 4;
        #pragma unroll
        for (int ni = 0; ni < 8; ++ni) {
            int chan = h * 128 + ni * 16 + lr;
            #pragma unroll
            for (int r = 0; r < 4; ++r) {
                long long row = (long long)(b * 512 + row0 + r);
                float zz = Z[row * 2048 + chan];
                float y = acc[ni][r] * (zz / (1.f + expf(-zz)));
                store_pair(YS2, row, 2048, chan, y);
            }
        }
    }
}

// ---------------------------------------------------------------------------
// Tiled f32 GEMM (small batched G = Cm @ Bm^T); z>=8 slices run cuma (one
// wave per (h,b) instance) — independent work fused into the same launch.
// ---------------------------------------------------------------------------
__global__ __launch_bounds__(256) void gemm_f32_k(
    int M, int N, int K,
    const float* __restrict__ A, int lda, long long sAb,
    const float* __restrict__ B, int ldb, long long sBb,
    float* __restrict__ C, int ldc, long long sCb,
    const float* __restrict__ DT, const float* __restrict__ A_log,
    float* __restrict__ CUMA)
{
    __shared__ float As[32][132];
    __shared__ float Bs[32][132];
    if (blockIdx.z >= 8) {
        // cuma: h = by*4+bx (0..15), b = (z-8)*4 + wave (0..7)
        const int wave = threadIdx.x >> 6;
        const int ln = threadIdx.x & 63;
        const int h = blockIdx.y * 4 + blockIdx.x;
        const int b = (blockIdx.z - 8) * 4 + wave;
        float Ah = -expf(A_log[h]);
        float v[8];
        float run = 0.f;
        #pragma unroll
        for (int i = 0; i < 8; ++i) {
            run += Ah * DT[((b * 512) + (ln * 8 + i)) * 16 + h];
            v[i] = run;
        }
        float tot = run;
        float sc = tot;
        #pragma unroll
        for (int o = 1; o <= 32; o <<= 1) {
            float u = __shfl_up(sc, o, 64);
            if (ln >= o) sc += u;
        }
        float excl = sc - tot;
        #pragma unroll
        for (int i = 0; i < 8; ++i)
            CUMA[(b * 16 + h) * 512 + ln * 8 + i] = excl + v[i];
        return;
    }
    const int z = blockIdx.z;
    A += z * sAb; B += z * sBb; C += z * sCb;
    const int n0 = blockIdx.x * 128;
    const int m0 = blockIdx.y * 128;
    const int t  = threadIdx.x;
    const int tx = t & 15, ty = t >> 4;

    float acc[4][16];
    #pragma unroll
    for (int a = 0; a < 4; ++a)
        #pragma unroll
        for (int q = 0; q < 16; ++q) acc[a][q] = 0.f;

    const int ka = (t & 7) << 2;
    const int ra = t >> 3;

    for (int k0 = 0; k0 < K; k0 += 32) {
        __syncthreads();
        #pragma unroll
        for (int i = 0; i < 4; ++i) {
            int row = m0 + ra + i * 32;
            float4 v = *(const float4*)(A + (long long)row * lda + (k0 + ka));
            As[ka + 0][ra + i * 32] = v.x;
            As[ka + 1][ra + i * 32] = v.y;
            As[ka + 2][ra + i * 32] = v.z;
            As[ka + 3][ra + i * 32] = v.w;
            int rowb = n0 + ra + i * 32;
            float4 w = *(const float4*)(B + (long long)rowb * ldb + (k0 + ka));
            Bs[ka + 0][ra + i * 32] = w.x;
            Bs[ka + 1][ra + i * 32] = w.y;
            Bs[ka + 2][ra + i * 32] = w.z;
            Bs[ka + 3][ra + i * 32] = w.w;
        }
        __syncthreads();
        #pragma unroll
        for (int kk = 0; kk < 32; ++kk) {
            float a[8], bm[8];
            *(float4*)&a[0]  = *(const float4*)&As[kk][ty * 4];
            *(float4*)&a[4]  = *(const float4*)&As[kk][64 + ty * 4];
            *(float4*)&bm[0] = *(const float4*)&Bs[kk][tx * 4];
            *(float4*)&bm[4] = *(const float4*)&Bs[kk][64 + tx * 4];
            #pragma unroll
            for (int ri = 0; ri < 2; ++ri)
                #pragma unroll
                for (int ci = 0; ci < 2; ++ci)
                    #pragma unroll
                    for (int i = 0; i < 4; ++i)
                        #pragma unroll
                        for (int j = 0; j < 4; ++j)
                            acc[ri * 2 + ci][i * 4 + j] =
                                fmaf(a[ri * 4 + i], bm[ci * 4 + j], acc[ri * 2 + ci][i * 4 + j]);
        }
    }
    #pragma unroll
    for (int ri = 0; ri < 2; ++ri)
        #pragma unroll
        for (int ci = 0; ci < 2; ++ci) {
            int colb = n0 + ci * 64 + tx * 4;
            #pragma unroll
            for (int i = 0; i < 4; ++i) {
                int row = m0 + ri * 64 + ty * 4 + i;
                *(float4*)(C + (long long)row * ldc + colb) =
                    *(float4*)&acc[ri * 2 + ci][i * 4];
            }
        }
}

// ---------------------------------------------------------------------------
// Elementwise / norm kernels
// ---------------------------------------------------------------------------

// Batched pairify: one launch, segment per blockIdx.y.
struct PairSegs {
    const float* src[7];
    unsigned short* dst[7];
    long long n[7];
    int klog2[7];
};
__global__ __launch_bounds__(256) void pairify_multi_k(PairSegs segs)
{
    int sg = blockIdx.y;
    long long idx = (long long)blockIdx.x * 256 + threadIdx.x;
    if (idx >= segs.n[sg]) return;
    int kl = segs.klog2[sg];
    long long r = idx >> kl;
    int c = (int)(idx & ((1LL << kl) - 1));
    store_pair(segs.dst[sg], r, 1 << kl, c, segs.src[sg][idx]);
}

// Fused preprocessing: blocks 0..4095 = LayerNorm2048(x)->XV2 pairs;
// blocks 4096.. = phase-A pairify (4 segments, linear block ranges).
__global__ __launch_bounds__(256) void prep_a_k(
    const float* __restrict__ x, unsigned short* __restrict__ XV2,
    const float* __restrict__ w, const float* __restrict__ b,
    PairSegs segs)
{
    const int t = threadIdx.x;
    if (blockIdx.x >= 4096) {
        int pb = blockIdx.x - 4096;
        // cumulative block counts: 8192, 1152, 256, 256
        int sg, base;
        if (pb < 8192)       { sg = 0; base = 0; }
        else if (pb < 9344)  { sg = 1; base = 8192; }
        else if (pb < 9600)  { sg = 2; base = 9344; }
        else                 { sg = 3; base = 9600; }
        long long idx = (long long)(pb - base) * 256 + t;
        if (idx >= segs.n[sg]) return;
        int kl = segs.klog2[sg];
        long long r = idx >> kl;
        int c = (int)(idx & ((1LL << kl) - 1));
        store_pair(segs.dst[sg], r, 1 << kl, c, segs.src[sg][idx]);
        return;
    }
    long long r = blockIdx.x;
    const float* xr = x + (r / 512) * (long long)(1024 * 2048)
                    + (r % 512) * 2048LL;
    float v[8];
    float s = 0.f;
    #pragma unroll
    for (int j = 0; j < 2; ++j) {
        float4 f = *(const float4*)(xr + j * 1024 + t * 4);
        v[j * 4 + 0] = f.x; v[j * 4 + 1] = f.y;
        v[j * 4 + 2] = f.z; v[j * 4 + 3] = f.w;
        s += f.x + f.y + f.z + f.w;
    }
    s = block_sum256(s);
    float m = s * (1.f / 2048.f);
    float vs = 0.f;
    #pragma unroll
    for (int e = 0; e < 8; ++e) { float d = v[e] - m; vs += d * d; }
    vs = block_sum256(vs);
    float rs = 1.f / sqrtf(vs * (1.f / 2048.f) + 1e-5f);
    #pragma unroll
    for (int j = 0; j < 2; ++j)
        #pragma unroll
        for (int e = 0; e < 4; ++e) {
            int c = j * 1024 + t * 4 + e;
            store_pair(XV2, r, 2048, c, (v[j * 4 + e] - m) * rs * w[c] + b[c]);
        }
}

// Fused: blocks 0..4095 = LayerNorm1024(DXV)->LNDXV2 pairs; block 4096 =
// dxm = mtok @ e2d^T + LayerNorm -> dxm, lnm.
__global__ __launch_bounds__(256) void lnd_dxm_k(
    const float* __restrict__ DXV, unsigned short* __restrict__ LNDXV2,
    const float* __restrict__ w, const float* __restrict__ b,
    const float* __restrict__ mtok, const float* __restrict__ e2d,
    float* __restrict__ dxm, float* __restrict__ lnm)
{
    const int t = threadIdx.x;
    if (blockIdx.x == 4096) {
        float mv[64];
        #pragma unroll
        for (int j = 0; j < 64; ++j) mv[j] = mtok[j];
        float loc[4];
        #pragma unroll
        for (int q = 0; q < 4; ++q) {
            int c = q * 256 + t;
            const float* er = e2d + (long long)c * 64;
            float acc = 0.f;
            #pragma unroll
            for (int j = 0; j < 64; ++j) acc = fmaf(mv[j], er[j], acc);
            loc[q] = acc;
            dxm[c] = acc;
        }
        float s = loc[0] + loc[1] + loc[2] + loc[3];
        s = block_sum256(s);
        float m = s * (1.f / 1024.f);
        float vs = 0.f;
        #pragma unroll
        for (int q = 0; q < 4; ++q) { float d = loc[q] - m; vs += d * d; }
        vs = block_sum256(vs);
        float rs = 1.f / sqrtf(vs * (1.f / 1024.f) + 1e-5f);
        #pragma unroll
        for (int q = 0; q < 4; ++q) {
            int c = q * 256 + t;
            lnm[c] = (loc[q] - m) * rs * w[c] + b[c];
        }
        return;
    }
    long long r = blockIdx.x;
    const float* xr = DXV + r * 1024LL;
    float v[4];
    float s = 0.f;
    {
        float4 f = *(const float4*)(xr + t * 4);
        v[0] = f.x; v[1] = f.y; v[2] = f.z; v[3] = f.w;
        s = f.x + f.y + f.z + f.w;
    }
    s = block_sum256(s);
    float m = s * (1.f / 1024.f);
    float vs = 0.f;
    #pragma unroll
    for (int e = 0; e < 4; ++e) { float d = v[e] - m; vs += d * d; }
    vs = block_sum256(vs);
    float rs = 1.f / sqrtf(vs * (1.f / 1024.f) + 1e-5f);
    #pragma unroll
    for (int e = 0; e < 4; ++e) {
        int c = t * 4 + e;
        store_pair(LNDXV2, r, 1024, c, (v[e] - m) * rs * w[c] + b[c]);
    }
}

// Softmax over 512-wide rows, f32 in -> split-pair out IN-PLACE (same bytes).
__global__ __launch_bounds__(256) void softmax_pair_k(float* __restrict__ S,
                                                      unsigned short* __restrict__ P2)
{
    long long r = blockIdx.x;
    float* x = S + r * 512;
    unsigned short* p = P2 + r * 1024;
    int t = threadIdx.x;
    float v0 = x[t], v1 = x[t + 256];
    float mx = block_max256(fmaxf(v0, v1));
    v0 = expf(v0 - mx); v1 = expf(v1 - mx);
    float sum = block_sum256(v0 + v1);
    float inv = 1.f / sum;
    v0 *= inv; v1 *= inv;
    __syncthreads();
    unsigned short h0 = bf16_rne(v0);
    p[t] = h0;       p[512 + t] = bf16_rne(v0 - bf16_tof(h0));
    unsigned short h1 = bf16_rne(v1);
    p[t + 256] = h1; p[512 + t + 256] = bf16_rne(v1 - bf16_tof(h1));
}

// Causal grouped conv with LDS-tile transpose: writes seq-major pairs XC2
// AND chan-major pairs XCT2, both coalesced.
__global__ __launch_bounds__(256) void conv_k(
    const float* __restrict__ XS, const float* __restrict__ W,
    unsigned short* __restrict__ XC2, unsigned short* __restrict__ XCT2)
{
    __shared__ float tile[64][65];
    const int o0  = blockIdx.x * 64;
    const int tt0 = blockIdx.y * 64;
    const int b   = blockIdx.z;
    const int t   = threadIdx.x;

    const int o  = o0 + (t & 63);
    const int g2 = (o >> 1) << 1;
    const float* Wo = W + o * 8;
    float w0 = Wo[0], w1 = Wo[1], w2 = Wo[2], w3 = Wo[3];
    float w4 = Wo[4], w5 = Wo[5], w6 = Wo[6], w7 = Wo[7];
    #pragma unroll
    for (int i = 0; i < 16; ++i) {
        int sl = (t >> 6) + 4 * i;
        int tt = tt0 + sl;
        const float* xb = XS + ((long long)(b * 512 + tt)) * 2048 + g2;
        float acc = w3 * xb[0] + w7 * xb[1];
        if (tt >= 1) acc += w2 * xb[-2048] + w6 * xb[-2047];
        if (tt >= 2) acc += w1 * xb[-4096] + w5 * xb[-4095];
        if (tt >= 3) acc += w0 * xb[-6144] + w4 * xb[-6143];
        tile[sl][t & 63] = acc;
    }
    __syncthreads();
    #pragma unroll
    for (int i = 0; i < 16; ++i) {
        int idx = t + 256 * i;
        int sl = idx >> 6, ol = idx & 63;
        float v = tile[sl][ol];
        unsigned short hi = bf16_rne(v);
        unsigned short lo = bf16_rne(v - bf16_tof(hi));
        long long row = (long long)(b * 512 + tt0 + sl);
        XC2[row * 4096 + o0 + ol] = hi;
        XC2[row * 4096 + 2048 + o0 + ol] = lo;
    }
    #pragma unroll
    for (int i = 0; i < 16; ++i) {
        int idx = t + 256 * i;
        int cl = idx >> 6, s = idx & 63;
        float v = tile[s][cl];
        unsigned short hi = bf16_rne(v);
        unsigned short lo = bf16_rne(v - bf16_tof(hi));
        long long tb = (long long)b * 2097152 + (long long)(o0 + cl) * 1024 + tt0 + s;
        XCT2[tb] = hi;
        XCT2[tb + 512] = lo;
    }
}

__global__ __launch_bounds__(256) void projm_k(
    const float* __restrict__ lnm,
    const float* __restrict__ bWq, const float* __restrict__ bWk, const float* __restrict__ bWv,
    float* __restrict__ qm, float* __restrict__ km, float* __restrict__ vm)
{
    int idx = blockIdx.x * 256 + threadIdx.x;
    int sel = idx >> 10, c = idx & 1023;
    const float* W = (sel == 0) ? bWq : (sel == 1) ? bWk : bWv;
    float* O = (sel == 0) ? qm : (sel == 1) ? km : vm;
    const float* wr = W + (long long)c * 1024;
    float acc = 0.f;
    for (int j = 0; j < 1024; j += 4) {
        float4 a = *(const float4*)(lnm + j);
        float4 w4 = *(const float4*)(wr + j);
        acc = fmaf(a.x, w4.x, fmaf(a.y, w4.y, fmaf(a.z, w4.z, fmaf(a.w, w4.w, acc))));
    }
    O[c] = acc;
}

// Collapsed decoder attention on fused KV buffer: KVm[row][0..1023]=K,
// [1024..2047]=V. 1 query/(b,h); keys = 512 visible + mask key x512.
__global__ __launch_bounds__(256) void dec_attn_k(
    const float* __restrict__ KVm,
    const float* __restrict__ qm, const float* __restrict__ km,
    const float* __restrict__ vm, float* __restrict__ OBm)
{
    int h = blockIdx.x, b = blockIdx.y;
    int t = threadIdx.x;
    __shared__ __align__(16) float qs[256];
    __shared__ __align__(16) float ps[512];
    qs[t] = qm[h * 256 + t];
    __syncthreads();
    float s[2];
    #pragma unroll
    for (int i = 0; i < 2; ++i) {
        int r = t + i * 256;
        const float* kr = KVm + ((long long)(b * 512 + r)) * 2048 + h * 256;
        float acc = 0.f;
        for (int c = 0; c < 256; c += 4) {
            float4 k4 = *(const float4*)(kr + c);
            float4 q4 = *(const float4*)(qs + c);
            acc = fmaf(k4.x, q4.x, fmaf(k4.y, q4.y, fmaf(k4.z, q4.z, fmaf(k4.w, q4.w, acc))));
        }
        s[i] = acc * (1.f / 16.f);
    }
    float accm = 0.f;
    for (int c = 0; c < 256; c += 4) {
        float4 k4 = *(const float4*)(km + h * 256 + c);
        float4 q4 = *(const float4*)(qs + c);
        accm = fmaf(k4.x, q4.x, fmaf(k4.y, q4.y, fmaf(k4.z, q4.z, fmaf(k4.w, q4.w, accm))));
    }
    float smv = accm * (1.f / 16.f);
    float mx = block_max256(fmaxf(fmaxf(s[0], s[1]), smv));
    float p0 = expf(s[0] - mx), p1 = expf(s[1] - mx);
    ps[t] = p0; ps[t + 256] = p1;
    float pm = expf(smv - mx) * 512.f;
    float sum = block_sum256(p0 + p1) + pm;
    float inv = 1.f / sum;
    __syncthreads();
    float o = pm * vm[h * 256 + t];
    const float* vcol = KVm + (long long)b * 512 * 2048 + 1024 + h * 256 + t;
    for (int j = 0; j < 512; ++j)
        o = fmaf(ps[j], vcol[(long long)j * 2048], o);
    OBm[b * 1024 + h * 256 + t] = o * inv;
}

__global__ __launch_bounds__(256) void ydm_k(
    const float* __restrict__ OBm, const float* __restrict__ bWo,
    const float* __restrict__ bWo_b, const float* __restrict__ dxm,
    float* __restrict__ ydm)
{
    int idx = blockIdx.x * 256 + threadIdx.x;
    int b = idx >> 10, c = idx & 1023;
    const float* ar = OBm + b * 1024;
    const float* wr = bWo + (long long)c * 1024;
    float acc = 0.f;
    for (int j = 0; j < 1024; j += 4) {
        float4 a = *(const float4*)(ar + j);
        float4 w4 = *(const float4*)(wr + j);
        acc = fmaf(a.x, w4.x, fmaf(a.y, w4.y, fmaf(a.z, w4.z, fmaf(a.w, w4.w, acc))));
    }
    ydm[idx] = acc + bWo_b[c] + dxm[c];
}

__global__ __launch_bounds__(256) void outm_k(
    const float* __restrict__ ydm, const float* __restrict__ dout_W,
    const float* __restrict__ dout_b, float* __restrict__ outm)
{
    int idx = blockIdx.x * 256 + threadIdx.x;
    int b = idx >> 11, c = idx & 2047;
    const float* ar = ydm + b * 1024;
    const float* wr = dout_W + (long long)c * 1024;
    float acc = 0.f;
    for (int j = 0; j < 1024; j += 4) {
        float4 a = *(const float4*)(ar + j);
        float4 w4 = *(const float4*)(wr + j);
        acc = fmaf(a.x, w4.x, fmaf(a.y, w4.y, fmaf(a.z, w4.z, fmaf(a.w, w4.w, acc))));
    }
    outm[idx] = acc + dout_b[c];
}

__global__ __launch_bounds__(256) void bcast_k(
    const float* __restrict__ outm, float* __restrict__ out)
{
    int idx = blockIdx.x * 256 + threadIdx.x;
    int c4 = idx & 511;
    int b = idx >> 18;
    ((float4*)out)[idx] = ((const float4*)outm)[b * 512 + c4];
}

// ---------------------------------------------------------------------------
// Host-side launcher
// ---------------------------------------------------------------------------
extern "C" void kernel_launch(void* const* d_in, const int* in_sizes, int n_in,
                              void* d_out, int out_size, void* d_ws, size_t ws_size,
                              hipStream_t stream)
{
    const float* x       = (const float*)d_in[0];
    const float* ln0_w   = (const float*)d_in[1];
    const float* ln0_b   = (const float*)d_in[2];
    const float* in_W    = (const float*)d_in[3];
    const float* rms_w   = (const float*)d_in[4];
    const float* exp_W   = (const float*)d_in[5];
    const float* conv_W  = (const float*)d_in[6];
    const float* xproj_W = (const float*)d_in[7];
    const float* dt_bias = (const float*)d_in[8];
    const float* A_log   = (const float*)d_in[9];
    const float* Dv      = (const float*)d_in[10];
    const float* outp_W  = (const float*)d_in[11];
    const float* outp_b  = (const float*)d_in[12];
    const float* n1_w    = (const float*)d_in[13];
    const float* n1_b    = (const float*)d_in[14];
    const float* aWq     = (const float*)d_in[15];
    const float* aWk     = (const float*)d_in[16];
    const float* aWv     = (const float*)d_in[17];
    const float* aWo     = (const float*)d_in[18];
    const float* aWo_b   = (const float*)d_in[19];
    const float* h_W     = (const float*)d_in[20];
    const float* h_b     = (const float*)d_in[21];
    const float* h_lnw   = (const float*)d_in[22];
    const float* h_lnb   = (const float*)d_in[23];
    const float* mtok    = (const float*)d_in[24];
    const float* e2d_W   = (const float*)d_in[25];
    const float* dn_w    = (const float*)d_in[26];
    const float* dn_b    = (const float*)d_in[27];
    const float* bWq     = (const float*)d_in[28];
    const float* bWk     = (const float*)d_in[29];
    const float* bWv     = (const float*)d_in[30];
    const float* bWo     = (const float*)d_in[31];
    const float* bWo_b   = (const float*)d_in[32];
    const float* dout_W  = (const float*)d_in[33];
    const float* dout_b  = (const float*)d_in[34];

    float* ws  = (float*)d_ws;
    float* out = (float*)d_out;

    float* S1 = ws;
    float* S2 = ws + 8388608;
    float* S3 = ws + 16777216;
    float* S4 = ws + 25165824;
    float* S5 = ws + 33554432;
    float* S6 = ws + 37748736;
    float* S7 = ws + 41943040;
    float* S8 = ws + 46137344;
    float* S9 = ws + 50331648;
    float* SP = ws + 54525952;

    unsigned short* XV2     = (unsigned short*)S1;
    unsigned short* exp_W2  = (unsigned short*)S1;
    unsigned short* XCT2    = (unsigned short*)S1;
    float*          POUTP   = S1;            // outp split-K partials
    float*          SA      = S1;
    unsigned short* P2      = (unsigned short*)S1;
    float*          KVm     = S1;            // fused K|V decoder buffer (32MB)
    unsigned short* in_W2   = (unsigned short*)S2;
    float*          XS      = S2;
    unsigned short* YS2     = (unsigned short*)S2;
    float*          PX      = S2;            // xproj split-K partials
    unsigned short* QKA2    = (unsigned short*)S2;  // merged Q|K pairs (32MB)
    unsigned short* XC2     = (unsigned short*)S3;
    float*          PIN     = S3;            // in split-K partials
    unsigned short* outp_W2 = (unsigned short*)S3;
    float*          PATT    = S3;            // aWv / aWo split-K partials
    float*          PH      = S3;            // hW split-K partials
    float*          DXV     = S3;
    unsigned short* LNDXV2  = (unsigned short*)(S3 + 4194304);
    float*          Z       = S4;
    unsigned short* aWq2    = (unsigned short*)S4;
    unsigned short* aWk2    = (unsigned short*)S4 + 2097152;
    unsigned short* aWv2    = (unsigned short*)S4 + 4194304;
    unsigned short* aWo2    = (unsigned short*)S4 + 6291456;
    unsigned short* bWk2    = (unsigned short*)S4 + 8388608;
    unsigned short* bWv2    = (unsigned short*)S4 + 10485760;
    float*          T       = S5;
    unsigned short* Y22     = (unsigned short*)S5;
    unsigned short* HR2     = (unsigned short*)S6;
    float*          Y1      = S6;
    unsigned short* LNY2    = (unsigned short*)S7;
    unsigned short* OA2     = (unsigned short*)S7;
    unsigned short* VT2     = (unsigned short*)S9;

    float* dtBC = SP;
    float* DT   = SP + 589824;
    float* CUMA = SP + 655360;
    float* G    = SP + 720896;
    unsigned short* xprojW2 = (unsigned short*)(SP + 2818048);
    unsigned short* hW2     = (unsigned short*)(SP + 3112960);
    unsigned short* e2dW2   = (unsigned short*)(SP + 3178496);
    unsigned short* HCQ2 = (unsigned short*)(SP + 983040);
    float* dxm  = SP + 1245184;
    float* lnm  = SP + 1246208;
    float* qm   = SP + 1247232;
    float* km   = SP + 1248256;
    float* vm   = SP + 1249280;
    float* OBm  = SP + 1250304;
    float* ydm  = SP + 1258496;
    float* outm = SP + 1266688;

    const long long LL0 = 0;
    const long long P4M = 4194304;
    #define G3D(OUTM, GX, GY, GZ, ...) \
        gemm_bf16_k<3, OUTM, true><<<dim3(GX, GY, GZ), 256, 0, stream>>>(__VA_ARGS__)
    #define G2D(OUTM, GX, GY, GZ, ...) \
        gemm_bf16_k<2, OUTM, true><<<dim3(GX, GY, GZ), 256, 0, stream>>>(__VA_ARGS__)
    #define G1D(OUTM, GX, GY, GZ, ...) \
        gemm_bf16_k<1, OUTM, true><<<dim3(GX, GY, GZ), 256, 0, stream>>>(__VA_ARGS__)

    // ---- fused preprocessing: LN(x) + phase-A weight pairify ----
    {
        PairSegs sA = {};
        sA.src[0] = in_W;    sA.dst[0] = in_W2;   sA.n[0] = 1024LL * 2048; sA.klog2[0] = 11;
        sA.src[1] = xproj_W; sA.dst[1] = xprojW2; sA.n[1] = 144LL * 2048;  sA.klog2[1] = 11;
        sA.src[2] = h_W;     sA.dst[2] = hW2;     sA.n[2] = 64LL * 1024;   sA.klog2[2] = 10;
        sA.src[3] = e2d_W;   sA.dst[3] = e2dW2;   sA.n[3] = 1024LL * 64;   sA.klog2[3] = 6;
        prep_a_k<<<4096 + 9856, 256, 0, stream>>>(x, XV2, ln0_w, ln0_b, sA);
    }

    // ---- encoder trunk ----
    // in: M=4096 N=1024 K=2048 -> DIRECT split-K x2, fused reduce+RMSNorm
    // (+ exp_W pairify fused into the same launch)
    gemm_bf16_skd_k<3, 0><<<dim3(8, 32, 2), 256, 0, stream>>>(
        1024, 1024, XV2, 4096, 2048, in_W2, 4096, 2048, PIN, P4M);
    skred_rms_pair_k<<<4096 + 16384, 256, 0, stream>>>(
        PIN, P4M, T, HR2, rms_w, exp_W, exp_W2);
    // merged exp GEMM: z=0 -> XS, z=1 -> Z (A read once)
    G3D(0, 16, 32, 2, 4096, 2048, 1024, HR2, 2048, 1024, LL0, LL0,
        exp_W2, 2048, 1024, (long long)2048 * 2048, LL0,
        XS, 2048, 0, 16777216LL, LL0,
        nullptr, nullptr, 0, 1.f, 1);
    conv_k<<<dim3(32, 8, 8), 256, 0, stream>>>(XS, conv_W, XC2, XCT2);
    // xproj: ragged split-K x8, fused reduce + softplus->DT
    gemm_bf16_sk_k<3><<<dim3(2, 32, 8), 256, 0, stream>>>(
        144, 256, XC2, 4096, 2048, xprojW2, 4096, 2048, PX, 589824LL);
    skred_dt_k<<<2304, 256, 0, stream>>>(PX, 589824LL, dt_bias, dtBC, DT,
                                         589824LL);
    // G = Cm @ Bm^T (z<8) + cuma (z in 8..9) in one launch
    gemm_f32_k<<<dim3(4, 4, 10), 256, 0, stream>>>(
        512, 512, 64, dtBC + 80, 144, (long long)512 * 144,
        dtBC + 16, 144, (long long)512 * 144, G, 512, (long long)512 * 512,
        DT, A_log, CUMA);
    ssd_mfma_k<<<dim3(4, 16, 8), 256, 0, stream>>>(G, CUMA, DT, XCT2, Z, Dv, YS2);

    // ---- weight prep (phase B: S3/S4 now dead, one batched launch) ----
    {
        PairSegs sB = {};
        sB.src[0] = outp_W; sB.dst[0] = outp_W2; sB.n[0] = 1024LL * 2048; sB.klog2[0] = 11;
        sB.src[1] = aWq;    sB.dst[1] = aWq2;    sB.n[1] = 1024LL * 1024; sB.klog2[1] = 10;
        sB.src[2] = aWk;    sB.dst[2] = aWk2;    sB.n[2] = 1024LL * 1024; sB.klog2[2] = 10;
        sB.src[3] = aWv;    sB.dst[3] = aWv2;    sB.n[3] = 1024LL * 1024; sB.klog2[3] = 10;
        sB.src[4] = aWo;    sB.dst[4] = aWo2;    sB.n[4] = 1024LL * 1024; sB.klog2[4] = 10;
        sB.src[5] = bWk;    sB.dst[5] = bWk2;    sB.n[5] = 1024LL * 1024; sB.klog2[5] = 10;
        sB.src[6] = bWv;    sB.dst[6] = bWv2;    sB.n[6] = 1024LL * 1024; sB.klog2[6] = 10;
        pairify_multi_k<<<dim3(8192, 7), 256, 0, stream>>>(sB);
    }

    // outp: split-K x2, fused reduce + bias + residual + LayerNorm
    gemm_bf16_skd_k<3, 0><<<dim3(8, 32, 2), 256, 0, stream>>>(
        1024, 1024, YS2, 4096, 2048, outp_W2, 4096, 2048, POUTP, P4M);
    skred_ln_k<<<4096, 256, 0, stream>>>(POUTP, P4M, outp_b, T, Y1, LNY2,
                                         n1_w, n1_b);

    // ---- encoder attention (all MFMA) ----
    // merged Q|K projection: N=2048, OUT1 pairs into QKA2
    G3D(1, 16, 32, 1, 4096, 2048, 1024, LNY2, 2048, 1024, LL0, LL0,
        aWq2, 2048, 1024, LL0, LL0, QKA2, 4096, 2048, LL0, LL0,
        nullptr, nullptr, 0, 1.f, 1);
    // aWv: split-K x2 with transposed partials -> VT2
    gemm_bf16_skd_k<3, 1><<<dim3(8, 32, 2), 256, 0, stream>>>(
        1024, 512, LNY2, 2048, 1024, aWv2, 2048, 1024, PATT, P4M);
    skredT_k<<<16384, 256, 0, stream>>>(PATT, P4M, 2, VT2, P4M);
    // QK^T: Q at QKA2 col 0-1023, K at col 1024-2047
    G3D(0, 4, 4, 32, 512, 512, 256,
        QKA2, 4096, 2048, (long long)512 * 4096, 256,
        QKA2 + 1024, 4096, 2048, (long long)512 * 4096, 256,
        SA, 512, 0, (long long)4 * 512 * 512, (long long)512 * 512,
        nullptr, nullptr, 0, 1.f / 16.f, 4);
    softmax_pair_k<<<16384, 256, 0, stream>>>(SA, P2);
    G3D(1, 2, 4, 32, 512, 256, 512,
        P2, 1024, 512, (long long)4 * 512 * 1024, (long long)512 * 1024,
        VT2, 1024, 512, (long long)1024 * 1024, (long long)256 * 1024,
        OA2, 2048, 1024, (long long)512 * 2048, 256,
        nullptr, nullptr, 0, 1.f, 4);
    // aWo: split-K x2 -> skredP with bias + residual(Y1) -> Y22 pairs
    gemm_bf16_skd_k<3, 0><<<dim3(8, 32, 2), 256, 0, stream>>>(
        1024, 512, OA2, 2048, 1024, aWo2, 2048, 1024, PATT, P4M);
    skredP_k<<<16384, 256, 0, stream>>>(PATT, P4M, 2, aWo_b, Y1, Y22, P4M);

    // ---- quantize: hW split-K x8, fused reduce + LN64 + sign-quant ----
    gemm_bf16_sk_k<3><<<dim3(1, 32, 8), 256, 0, stream>>>(
        64, 128, Y22, 2048, 1024, hW2, 2048, 1024, PH, 262144LL);
    skred_hc_k<<<4096, 64, 0, stream>>>(PH, 262144LL, h_b, h_lnw, h_lnb, HCQ2);

    // ---- decoder (collapsed masked rows) ----
    // HCQ values are exactly representable (+-1, lo==0): NPASS=2 is
    // bit-identical to NPASS=3 here, 1/3 fewer MFMAs + less staging.
    G2D(0, 8, 32, 1, 4096, 1024, 64, HCQ2, 128, 64, LL0, LL0,
        e2dW2, 128, 64, LL0, LL0, DXV, 1024, 0, LL0, LL0,
        nullptr, nullptr, 0, 1.f, 1);
    lnd_dxm_k<<<4097, 256, 0, stream>>>(DXV, LNDXV2, dn_w, dn_b,
                                        mtok, e2d_W, dxm, lnm);
    projm_k<<<12, 256, 0, stream>>>(lnm, bWq, bWk, bWv, qm, km, vm);
    // merged K|V projection: N=2048, OUT0 f32 into fused KVm
    G1D(0, 16, 32, 1, 4096, 2048, 1024, LNDXV2, 2048, 1024, LL0, LL0,
        bWk2, 2048, 1024, LL0, LL0, KVm, 2048, 0, LL0, LL0,
        nullptr, nullptr, 0, 1.f, 1);
    dec_attn_k<<<dim3(4, 8), 256, 0, stream>>>(KVm, qm, km, vm, OBm);
    ydm_k<<<32, 256, 0, stream>>>(OBm, bWo, bWo_b, dxm, ydm);
    outm_k<<<64, 256, 0, stream>>>(ydm, dout_W, dout_b, outm);
    bcast_k<<<8192, 256, 0, stream>>>(outm, out);
    #undef G3D
    #undef G2D
    #undef G1D
}